// Round 3
// baseline (173.948 us; speedup 1.0000x reference)
//
#include <hip/hip_runtime.h>
#include <hip/hip_bf16.h>
#include <cstdint>

typedef unsigned short u16;
typedef __attribute__((ext_vector_type(4))) float f32x4;
typedef __attribute__((ext_vector_type(8))) short s16x8;
typedef __attribute__((ext_vector_type(4))) unsigned int u32x4;

#define B_    2
#define LQ_   2048
#define LKV_  2048
#define H_    16
// softmax scale folded into Q at GEMM epilogue: 0.125 * log2(e)
#define QSCALE_ 0.18033688011112042f

__device__ __forceinline__ u16 f2b(float f) {
  union { float f; unsigned int u; } v; v.f = f;
  unsigned int r = v.u + 0x7fffu + ((v.u >> 16) & 1u);
  return (u16)(r >> 16);
}

__device__ __forceinline__ unsigned cvtpk(float lo, float hi) {
  unsigned r;
  asm("v_cvt_pk_bf16_f32 %0, %1, %2" : "=v"(r) : "v"(lo), "v"(hi));
  return r;
}

// ---------------- elementwise cast fp32 -> bf16 ----------------
__global__ void cast_bf16(const float* __restrict__ in, u16* __restrict__ out, int n) {
  int i = (blockIdx.x * 256 + threadIdx.x) * 4;
  if (i >= n) return;
  float4 v = *reinterpret_cast<const float4*>(in + i);
  ushort4 r;
  r.x = f2b(v.x); r.y = f2b(v.y); r.z = f2b(v.z); r.w = f2b(v.w);
  *reinterpret_cast<ushort4*>(out + i) = r;
}

// ---------------- transpose + cast: W[K][N] f32 -> WT[N][K] bf16 ----------------
__global__ void transpose_cast(const float* __restrict__ W, u16* __restrict__ WT, int K, int N) {
  __shared__ u16 tile[64][65];
  const int t = threadIdx.x;
  const int n0 = blockIdx.x * 64, k0 = blockIdx.y * 64;
#pragma unroll
  for (int p = 0; p < 4; ++p) {
    int r = (t >> 4) + p * 16;
    int c = (t & 15) * 4;
    float4 v = *reinterpret_cast<const float4*>(W + (size_t)(k0 + r) * N + n0 + c);
    tile[r][c + 0] = f2b(v.x);
    tile[r][c + 1] = f2b(v.y);
    tile[r][c + 2] = f2b(v.z);
    tile[r][c + 3] = f2b(v.w);
  }
  __syncthreads();
#pragma unroll
  for (int p = 0; p < 4; ++p) {
    int nr = (t >> 4) + p * 16;
    int kc = (t & 15) * 4;
    ushort4 o;
    o.x = tile[kc + 0][nr];
    o.y = tile[kc + 1][nr];
    o.z = tile[kc + 2][nr];
    o.w = tile[kc + 3][nr];
    *reinterpret_cast<ushort4*>(WT + (size_t)(n0 + nr) * K + k0 + kc) = o;
  }
}

// ---------------- GEMM: C[M,N] = A[M,K] * BT[N,K]^T (bf16 in, fp32 acc) ----------------
// OM==1: fp32 out + bias (proj)
// OM==2: KV split: cols<1024 -> K to Cb [M,1024]; cols>=1024 -> V transposed to VTp[bh][d][kv]
// OM==3: bf16 out scaled by QSCALE_ (Q projection)
template <int OM>
__global__ __launch_bounds__(256, 2)
void gemm_bt(const u16* __restrict__ A, const u16* __restrict__ BT,
             u16* __restrict__ Cb, float* __restrict__ Cf,
             const float* __restrict__ bias, u16* __restrict__ VTp,
             int M, int N, int K) {
  __shared__ u16 sA[128 * 32];
  __shared__ u16 sB[128 * 32];
  const int tid = threadIdx.x;
  const int w = tid >> 6, lane = tid & 63;
  const int l16 = lane & 15, lk = lane >> 4;
  const int m0 = blockIdx.x * 128, n0 = blockIdx.y * 128;
  const int wm = w >> 1, wn = w & 1;

  f32x4 acc[4][4];
#pragma unroll
  for (int i = 0; i < 4; ++i)
#pragma unroll
    for (int j = 0; j < 4; ++j)
      acc[i][j] = (f32x4){0.f, 0.f, 0.f, 0.f};

  const u16* ga0 = A  + (size_t)(m0 + w * 32 + (lane >> 2)) * K + (lane & 3) * 8;
  const u16* ga1 = ga0 + (size_t)16 * K;
  const u16* gb0 = BT + (size_t)(n0 + w * 32 + (lane >> 2)) * K + (lane & 3) * 8;
  const u16* gb1 = gb0 + (size_t)16 * K;
  u16* la0 = sA + (w * 32) * 32;
  u16* la1 = la0 + 16 * 32;
  u16* lb0 = sB + (w * 32) * 32;
  u16* lb1 = lb0 + 16 * 32;

  for (int k0 = 0; k0 < K; k0 += 32) {
    __builtin_amdgcn_global_load_lds((const __attribute__((address_space(1))) void*)ga0,
                                     (__attribute__((address_space(3))) void*)la0, 16, 0, 0);
    __builtin_amdgcn_global_load_lds((const __attribute__((address_space(1))) void*)ga1,
                                     (__attribute__((address_space(3))) void*)la1, 16, 0, 0);
    __builtin_amdgcn_global_load_lds((const __attribute__((address_space(1))) void*)gb0,
                                     (__attribute__((address_space(3))) void*)lb0, 16, 0, 0);
    __builtin_amdgcn_global_load_lds((const __attribute__((address_space(1))) void*)gb1,
                                     (__attribute__((address_space(3))) void*)lb1, 16, 0, 0);
    ga0 += 32; ga1 += 32; gb0 += 32; gb1 += 32;
    __syncthreads();

    s16x8 af[4], bf[4];
#pragma unroll
    for (int mt = 0; mt < 4; ++mt)
      af[mt] = *reinterpret_cast<const s16x8*>(sA + (wm * 64 + mt * 16 + l16) * 32 + lk * 8);
#pragma unroll
    for (int nt = 0; nt < 4; ++nt)
      bf[nt] = *reinterpret_cast<const s16x8*>(sB + (wn * 64 + nt * 16 + l16) * 32 + lk * 8);
#pragma unroll
    for (int mt = 0; mt < 4; ++mt)
#pragma unroll
      for (int nt = 0; nt < 4; ++nt)
        acc[mt][nt] = __builtin_amdgcn_mfma_f32_16x16x32_bf16(af[mt], bf[nt], acc[mt][nt], 0, 0, 0);
    __syncthreads();
  }

#pragma unroll
  for (int mt = 0; mt < 4; ++mt) {
#pragma unroll
    for (int nt = 0; nt < 4; ++nt) {
      const int col = n0 + wn * 64 + nt * 16 + l16;
      const int row0 = m0 + wm * 64 + mt * 16 + lk * 4;
      if (OM == 2 && col >= 1024) {
        // V part: 4 consecutive kv (j) -> one 8B store into VT[bh][d][kv]
        int b = row0 >> 11, kv = row0 & 2047;
        int h = (col >> 6) & 15, d = col & 63;
        ushort4 o;
        o.x = f2b(acc[mt][nt][0]); o.y = f2b(acc[mt][nt][1]);
        o.z = f2b(acc[mt][nt][2]); o.w = f2b(acc[mt][nt][3]);
        *reinterpret_cast<ushort4*>(VTp + (((size_t)(b * 16 + h) * 64 + d) * 2048 + kv)) = o;
      } else {
#pragma unroll
        for (int j = 0; j < 4; ++j) {
          int row = row0 + j;
          if (OM == 3)      Cb[(size_t)row * N + col] = f2b(acc[mt][nt][j] * QSCALE_);
          else if (OM == 2) Cb[(size_t)row * 1024 + col] = f2b(acc[mt][nt][j]);
          else              Cf[(size_t)row * N + col] = acc[mt][nt][j] + bias[col];
        }
      }
    }
  }
}

// ---------------- flash attention v3 ----------------
// 4 waves/block (256 thr), 32 q-rows/wave -> 128 q-rows/block, KVBLK=64, D=64.
// Q pre-scaled by 0.125*log2e -> softmax in exp2 domain.
// S^T = mfma(K_perm, Q^T); P stays in registers (kv(ct,o) permutation makes each
// lane's 16 S-slots exactly the PV B-fragment's kv set). O^T = mfma(VT, P^T).
__global__ __launch_bounds__(256)
void flash_attn(const u16* __restrict__ Kq, const u16* __restrict__ Qb,
                const u16* __restrict__ VT, u16* __restrict__ Rb) {
  __shared__ u16 sK[2][4096];   // [64 kv-rows][128B], chunk c' holds global chunk c'^(row&7)
  __shared__ u16 sV[2][4096];   // [64 d-rows][128B], same swizzle

  const int tid = threadIdx.x;
  const int w = tid >> 6, l = tid & 63;
  const int l16 = l & 15, lk = l >> 4;

  // bijective XCD swizzle: 512 blocks -> 64/XCD -> 4 heads per XCD L2
  const int bid = blockIdx.x;
  const int wg = ((bid & 7) << 6) | (bid >> 3);
  const int bx = wg & 15, bh = wg >> 4;
  const int b = bh >> 4, h = bh & 15;
  const int qrow0 = bx * 128 + w * 32;

  // Q B-fragments (col=q=l16, k=dk), resident all kernel
  const u16* qp = Qb + ((size_t)(b * LQ_ + qrow0 + l16)) * 1024 + h * 64;
  s16x8 qf[2][2];
#pragma unroll
  for (int g = 0; g < 2; ++g)
#pragma unroll
    for (int ks = 0; ks < 2; ++ks)
      qf[g][ks] = *reinterpret_cast<const s16x8*>(qp + g * 16 * 1024 + ks * 32 + lk * 8);

  f32x4 Oacc[2][4];
  float m_run[2] = {-1e30f, -1e30f}, d_run[2] = {0.f, 0.f};
#pragma unroll
  for (int g = 0; g < 2; ++g)
#pragma unroll
    for (int dt = 0; dt < 4; ++dt) Oacc[g][dt] = (f32x4){0.f, 0.f, 0.f, 0.f};

  const u16* Kg = Kq + ((size_t)b * LKV_) * 1024 + h * 64;   // K rows stride 1024
  const u16* Vg = VT + ((size_t)bh * 64) * 2048;             // VT rows (d) stride 2048

  // QK A-frag row constants
  const int r0 = ((l16 >> 2) << 3) + (l16 & 3);
  const int xpar = (l16 >> 2) & 1;
  const int swv = (l16 & 7) << 4;

  // staging: 256 threads, 2 rounds each of K and V (16B per thread per round)
  const int srow = tid >> 3;                 // 0..31
  const int scol = (tid & 7) ^ (srow & 7);   // pre-swizzled source chunk

  auto stage = [&](int jt, int bb) {
#pragma unroll
    for (int i = 0; i < 2; ++i) {
      int row = srow + i * 32;
      __builtin_amdgcn_global_load_lds(
          (const __attribute__((address_space(1))) void*)(Kg + ((size_t)(jt * 64 + row)) * 1024 + scol * 8),
          (__attribute__((address_space(3))) void*)(sK[bb] + w * 512 + i * 2048), 16, 0, 0);
      __builtin_amdgcn_global_load_lds(
          (const __attribute__((address_space(1))) void*)(Vg + ((size_t)row) * 2048 + jt * 64 + scol * 8),
          (__attribute__((address_space(3))) void*)(sV[bb] + w * 512 + i * 2048), 16, 0, 0);
    }
  };

  stage(0, 0);
  __syncthreads();

  int cur = 0;
  for (int jt = 0; jt < LKV_ / 64; ++jt) {
    if (jt < LKV_ / 64 - 1) stage(jt + 1, cur ^ 1);
    const char* kb = (const char*)sK[cur];
    const char* vb = (const char*)sV[cur];

    // ---- S^T = K_perm . Q^T ----
    f32x4 sacc[2][4];
#pragma unroll
    for (int g = 0; g < 2; ++g)
#pragma unroll
      for (int ct = 0; ct < 4; ++ct) sacc[g][ct] = (f32x4){0.f, 0.f, 0.f, 0.f};

    __builtin_amdgcn_s_setprio(1);
#pragma unroll
    for (int ct = 0; ct < 4; ++ct) {
      const int R = r0 + (((ct & 1) ^ xpar) << 2) + ((ct >> 1) << 5);
      const char* rp = kb + R * 128;
      const int sw = (R & 7) << 4;
      s16x8 ka0 = *reinterpret_cast<const s16x8*>(rp + ((lk * 16) ^ sw));
      s16x8 ka1 = *reinterpret_cast<const s16x8*>(rp + ((64 + lk * 16) ^ sw));
      sacc[0][ct] = __builtin_amdgcn_mfma_f32_16x16x32_bf16(ka0, qf[0][0], sacc[0][ct], 0, 0, 0);
      sacc[0][ct] = __builtin_amdgcn_mfma_f32_16x16x32_bf16(ka1, qf[0][1], sacc[0][ct], 0, 0, 0);
      sacc[1][ct] = __builtin_amdgcn_mfma_f32_16x16x32_bf16(ka0, qf[1][0], sacc[1][ct], 0, 0, 0);
      sacc[1][ct] = __builtin_amdgcn_mfma_f32_16x16x32_bf16(ka1, qf[1][1], sacc[1][ct], 0, 0, 0);
    }
    __builtin_amdgcn_s_setprio(0);

    // ---- online softmax in exp2 domain, defer-max (THR=8) ----
#pragma unroll
    for (int g = 0; g < 2; ++g) {
      float mx = sacc[g][0][0];
#pragma unroll
      for (int ct = 0; ct < 4; ++ct)
#pragma unroll
        for (int j = 0; j < 4; ++j) mx = fmaxf(mx, sacc[g][ct][j]);
      mx = fmaxf(mx, __shfl_xor(mx, 16, 64));
      mx = fmaxf(mx, __shfl_xor(mx, 32, 64));
      if (!__all(mx <= m_run[g] + 8.0f)) {
        float mnew = fmaxf(m_run[g], mx);
        float sc = exp2f(m_run[g] - mnew);
        m_run[g] = mnew;
        d_run[g] *= sc;
#pragma unroll
        for (int dt = 0; dt < 4; ++dt) Oacc[g][dt] *= sc;
      }
      const float m = m_run[g];
      float ps = 0.f;
#pragma unroll
      for (int ct = 0; ct < 4; ++ct)
#pragma unroll
        for (int j = 0; j < 4; ++j) {
          float e = exp2f(sacc[g][ct][j] - m);
          sacc[g][ct][j] = e;
          ps += e;
        }
      ps += __shfl_xor(ps, 16, 64);
      ps += __shfl_xor(ps, 32, 64);
      d_run[g] += ps;
    }

    // ---- O^T += VT . P^T (P stays in registers) ----
    const bool sel = (lk & 1) != 0;
#pragma unroll
    for (int f = 0; f < 2; ++f) {
      s16x8 pf[2];
#pragma unroll
      for (int g = 0; g < 2; ++g) {
        f32x4 pA = sel ? sacc[g][2 * f + 1] : sacc[g][2 * f];
        f32x4 pB = sel ? sacc[g][2 * f] : sacc[g][2 * f + 1];
        union { unsigned u[4]; s16x8 v; } pk;
        pk.u[0] = cvtpk(pA[0], pA[1]);
        pk.u[1] = cvtpk(pA[2], pA[3]);
        pk.u[2] = cvtpk(pB[0], pB[1]);
        pk.u[3] = cvtpk(pB[2], pB[3]);
        pf[g] = pk.v;
      }
      __builtin_amdgcn_s_setprio(1);
#pragma unroll
      for (int dt = 0; dt < 4; ++dt) {
        const char* vrp = vb + (dt * 16 + l16) * 128;
        s16x8 va = *reinterpret_cast<const s16x8*>(vrp + ((f * 64 + lk * 16) ^ swv));
        Oacc[0][dt] = __builtin_amdgcn_mfma_f32_16x16x32_bf16(va, pf[0], Oacc[0][dt], 0, 0, 0);
        Oacc[1][dt] = __builtin_amdgcn_mfma_f32_16x16x32_bf16(va, pf[1], Oacc[1][dt], 0, 0, 0);
      }
      __builtin_amdgcn_s_setprio(0);
    }
    __syncthreads();
    cur ^= 1;
  }

  // ---- epilogue: O[q=l16][d=16dt+4lk+j] / d_run ----
  u16* op = Rb + ((size_t)(b * LQ_ + qrow0 + l16)) * 1024 + h * 64 + lk * 4;
#pragma unroll
  for (int g = 0; g < 2; ++g) {
    float inv = 1.f / d_run[g];
#pragma unroll
    for (int dt = 0; dt < 4; ++dt) {
      ushort4 o;
      o.x = f2b(Oacc[g][dt][0] * inv);
      o.y = f2b(Oacc[g][dt][1] * inv);
      o.z = f2b(Oacc[g][dt][2] * inv);
      o.w = f2b(Oacc[g][dt][3] * inv);
      *reinterpret_cast<ushort4*>(op + g * 16 * 1024 + dt * 16) = o;
    }
  }
}

// ---------------- launch ----------------
extern "C" void kernel_launch(void* const* d_in, const int* in_sizes, int n_in,
                              void* d_out, int out_size, void* d_ws, size_t ws_size,
                              hipStream_t stream) {
  const float* x   = (const float*)d_in[0];
  const float* y   = (const float*)d_in[1];
  const float* Wq  = (const float*)d_in[2];
  const float* Wkv = (const float*)d_in[3];
  const float* Wp  = (const float*)d_in[4];
  const float* bp  = (const float*)d_in[5];
  float* out = (float*)d_out;

  u16* p = (u16*)d_ws;
  u16* xb   = p; p += (size_t)4096 * 1024;
  u16* yb   = p; p += (size_t)4096 * 768;
  u16* WqT  = p; p += (size_t)1024 * 1024;
  u16* WkvT = p; p += (size_t)2048 * 768;
  u16* WpT  = p; p += (size_t)1024 * 1024;
  u16* Qb   = p; p += (size_t)4096 * 1024;
  u16* Kbf  = p; p += (size_t)4096 * 1024;   // K compact [b*2048+kv][h*64+d]
  u16* VTb  = p; p += (size_t)4096 * 2048 - (size_t)4096 * 1024;  // [32][64][2048] = 4M elems
  u16* Rb   = p; p += (size_t)4096 * 1024;

  cast_bf16<<<4096, 256, 0, stream>>>(x, xb, 4096 * 1024);
  cast_bf16<<<3072, 256, 0, stream>>>(y, yb, 4096 * 768);
  transpose_cast<<<dim3(16, 16), 256, 0, stream>>>(Wq, WqT, 1024, 1024);
  transpose_cast<<<dim3(32, 12), 256, 0, stream>>>(Wkv, WkvT, 768, 2048);
  transpose_cast<<<dim3(16, 16), 256, 0, stream>>>(Wp, WpT, 1024, 1024);

  // Q = (x @ Wq) * 0.125*log2e : bf16 [4096,1024]
  gemm_bt<3><<<dim3(32, 8), 256, 0, stream>>>(xb, WqT, Qb, nullptr, nullptr, nullptr, 4096, 1024, 1024);
  // KV = y @ Wkv : K -> Kbf [4096,1024], V -> VTb [32][64][2048] (transposed in epilogue)
  gemm_bt<2><<<dim3(32, 16), 256, 0, stream>>>(yb, WkvT, Kbf, nullptr, nullptr, VTb, 4096, 2048, 768);
  // attention -> Rb [4096,1024]
  flash_attn<<<512, 256, 0, stream>>>(Kbf, Qb, VTb, Rb);
  // out = Rb @ Wproj + bias : fp32 [4096,1024]
  gemm_bt<1><<<dim3(32, 8), 256, 0, stream>>>(Rb, WpT, nullptr, out, bp, nullptr, 4096, 1024, 1024);
}

// Round 4
// 163.833 us; speedup vs baseline: 1.0617x; 1.0617x over previous
//
#include <hip/hip_runtime.h>
#include <hip/hip_bf16.h>
#include <cstdint>

typedef unsigned short u16;
typedef __attribute__((ext_vector_type(4))) float f32x4;
typedef __attribute__((ext_vector_type(8))) short s16x8;
typedef __attribute__((ext_vector_type(4))) unsigned int u32x4;

#define B_    2
#define LQ_   2048
#define LKV_  2048
#define H_    16
// softmax scale folded into Q at GEMM epilogue: 0.125 * log2(e)
#define QSCALE_ 0.18033688011112042f

__device__ __forceinline__ u16 f2b(float f) {
  union { float f; unsigned int u; } v; v.f = f;
  unsigned int r = v.u + 0x7fffu + ((v.u >> 16) & 1u);
  return (u16)(r >> 16);
}

__device__ __forceinline__ unsigned cvtpk(float lo, float hi) {
  unsigned r;
  asm("v_cvt_pk_bf16_f32 %0, %1, %2" : "=v"(r) : "v"(lo), "v"(hi));
  return r;
}

// ---------------- elementwise cast fp32 -> bf16 ----------------
__global__ void cast_bf16(const float* __restrict__ in, u16* __restrict__ out, int n) {
  int i = (blockIdx.x * 256 + threadIdx.x) * 4;
  if (i >= n) return;
  float4 v = *reinterpret_cast<const float4*>(in + i);
  ushort4 r;
  r.x = f2b(v.x); r.y = f2b(v.y); r.z = f2b(v.z); r.w = f2b(v.w);
  *reinterpret_cast<ushort4*>(out + i) = r;
}

// ---------------- transpose + cast: W[K][N] f32 -> WT[N][K] bf16 ----------------
__global__ void transpose_cast(const float* __restrict__ W, u16* __restrict__ WT, int K, int N) {
  __shared__ u16 tile[64][65];
  const int t = threadIdx.x;
  const int n0 = blockIdx.x * 64, k0 = blockIdx.y * 64;
#pragma unroll
  for (int p = 0; p < 4; ++p) {
    int r = (t >> 4) + p * 16;
    int c = (t & 15) * 4;
    float4 v = *reinterpret_cast<const float4*>(W + (size_t)(k0 + r) * N + n0 + c);
    tile[r][c + 0] = f2b(v.x);
    tile[r][c + 1] = f2b(v.y);
    tile[r][c + 2] = f2b(v.z);
    tile[r][c + 3] = f2b(v.w);
  }
  __syncthreads();
#pragma unroll
  for (int p = 0; p < 4; ++p) {
    int nr = (t >> 4) + p * 16;
    int kc = (t & 15) * 4;
    ushort4 o;
    o.x = tile[kc + 0][nr];
    o.y = tile[kc + 1][nr];
    o.z = tile[kc + 2][nr];
    o.w = tile[kc + 3][nr];
    *reinterpret_cast<ushort4*>(WT + (size_t)(n0 + nr) * K + k0 + kc) = o;
  }
}

// ---------------- GEMM: C[M,N] = A[M,K] * BT[N,K]^T, BM=128 BN=64 BK=32 ----------------
// OM==1: fp32 out + bias (proj)
// OM==2: KV split: cols<1024 -> K to Cb [M,1024]; cols>=1024 -> V transposed to VTp[bh][d][kv]
// OM==3: bf16 out scaled by QSCALE_ (Q projection)
template <int OM>
__global__ __launch_bounds__(256, 4)
void gemm_bt(const u16* __restrict__ A, const u16* __restrict__ BT,
             u16* __restrict__ Cb, float* __restrict__ Cf,
             const float* __restrict__ bias, u16* __restrict__ VTp,
             int M, int N, int K) {
  __shared__ u16 sA[128 * 32];
  __shared__ u16 sB[64 * 32];
  const int tid = threadIdx.x;
  const int w = tid >> 6, lane = tid & 63;
  const int l16 = lane & 15, lk = lane >> 4;
  const int m0 = blockIdx.x * 128, n0 = blockIdx.y * 64;
  const int wm = w >> 1, wn = w & 1;

  f32x4 acc[4][2];
#pragma unroll
  for (int i = 0; i < 4; ++i)
#pragma unroll
    for (int j = 0; j < 2; ++j)
      acc[i][j] = (f32x4){0.f, 0.f, 0.f, 0.f};

  // staging: A 128x32 (2 rounds), B 64x32 (1 round); 16B chunks, linear LDS
  const u16* ga0 = A  + (size_t)(m0 + (tid >> 2)) * K + (tid & 3) * 8;
  const u16* ga1 = ga0 + (size_t)64 * K;
  const u16* gb0 = BT + (size_t)(n0 + (tid >> 2)) * K + (tid & 3) * 8;
  u16* la0 = sA + tid * 8;
  u16* la1 = la0 + 64 * 32;
  u16* lb0 = sB + tid * 8;

  for (int k0 = 0; k0 < K; k0 += 32) {
    __builtin_amdgcn_global_load_lds((const __attribute__((address_space(1))) void*)ga0,
                                     (__attribute__((address_space(3))) void*)la0, 16, 0, 0);
    __builtin_amdgcn_global_load_lds((const __attribute__((address_space(1))) void*)ga1,
                                     (__attribute__((address_space(3))) void*)la1, 16, 0, 0);
    __builtin_amdgcn_global_load_lds((const __attribute__((address_space(1))) void*)gb0,
                                     (__attribute__((address_space(3))) void*)lb0, 16, 0, 0);
    ga0 += 32; ga1 += 32; gb0 += 32;
    __syncthreads();

    s16x8 af[4], bf[2];
#pragma unroll
    for (int mt = 0; mt < 4; ++mt)
      af[mt] = *reinterpret_cast<const s16x8*>(sA + (wm * 64 + mt * 16 + l16) * 32 + lk * 8);
#pragma unroll
    for (int nt = 0; nt < 2; ++nt)
      bf[nt] = *reinterpret_cast<const s16x8*>(sB + (wn * 32 + nt * 16 + l16) * 32 + lk * 8);
#pragma unroll
    for (int mt = 0; mt < 4; ++mt)
#pragma unroll
      for (int nt = 0; nt < 2; ++nt)
        acc[mt][nt] = __builtin_amdgcn_mfma_f32_16x16x32_bf16(af[mt], bf[nt], acc[mt][nt], 0, 0, 0);
    __syncthreads();
  }

#pragma unroll
  for (int mt = 0; mt < 4; ++mt) {
#pragma unroll
    for (int nt = 0; nt < 2; ++nt) {
      const int col = n0 + wn * 32 + nt * 16 + l16;
      const int row0 = m0 + wm * 64 + mt * 16 + lk * 4;
      if (OM == 2 && col >= 1024) {
        // V part: 4 consecutive kv (j) -> one 8B store into VT[bh][d][kv]
        int b = row0 >> 11, kv = row0 & 2047;
        int h = (col >> 6) & 15, d = col & 63;
        ushort4 o;
        o.x = f2b(acc[mt][nt][0]); o.y = f2b(acc[mt][nt][1]);
        o.z = f2b(acc[mt][nt][2]); o.w = f2b(acc[mt][nt][3]);
        *reinterpret_cast<ushort4*>(VTp + (((size_t)(b * 16 + h) * 64 + d) * 2048 + kv)) = o;
      } else {
#pragma unroll
        for (int j = 0; j < 4; ++j) {
          int row = row0 + j;
          if (OM == 3)      Cb[(size_t)row * N + col] = f2b(acc[mt][nt][j] * QSCALE_);
          else if (OM == 2) Cb[(size_t)row * 1024 + col] = f2b(acc[mt][nt][j]);
          else              Cf[(size_t)row * N + col] = acc[mt][nt][j] + bias[col];
        }
      }
    }
  }
}

// ---------------- flash attention v4 ----------------
// 4 waves/block (256 thr), 16 q-rows/wave -> 64 q-rows/block, KVBLK=64, D=64.
// 1024 blocks -> 4 blocks/CU, 16 waves/CU. Q pre-scaled by 0.125*log2e (exp2 domain).
// S^T = mfma(K_perm, Q^T) with C-in = -m_run (all of a lane's slots share q=l16).
// P stays in registers; O^T = mfma(VT, P^T).
__global__ __launch_bounds__(256)
void flash_attn(const u16* __restrict__ Kq, const u16* __restrict__ Qb,
                const u16* __restrict__ VT, u16* __restrict__ Rb) {
  __shared__ u16 sK[2][4096];   // [64 kv-rows][128B], chunk c' holds global chunk c'^(row&7)
  __shared__ u16 sV[2][4096];   // [64 d-rows][128B], same swizzle

  const int tid = threadIdx.x;
  const int w = tid >> 6, l = tid & 63;
  const int l16 = l & 15, lk = l >> 4;

  // bijective XCD swizzle: 1024 blocks -> 128/XCD -> 4 heads per XCD L2
  const int bid = blockIdx.x;
  const int wg = ((bid & 7) << 7) | (bid >> 3);
  const int bx = wg & 31, bh = wg >> 5;
  const int b = bh >> 4, h = bh & 15;
  const int qrow0 = bx * 64 + w * 16;

  // Q B-fragments (col=q=l16, k=dk), resident all kernel
  const u16* qp = Qb + ((size_t)(b * LQ_ + qrow0 + l16)) * 1024 + h * 64;
  s16x8 qf[2];
#pragma unroll
  for (int ks = 0; ks < 2; ++ks)
    qf[ks] = *reinterpret_cast<const s16x8*>(qp + ks * 32 + lk * 8);

  f32x4 Oacc[4];
  float m_run = 0.f, d_run = 0.f;
#pragma unroll
  for (int dt = 0; dt < 4; ++dt) Oacc[dt] = (f32x4){0.f, 0.f, 0.f, 0.f};

  const u16* Kg = Kq + ((size_t)b * LKV_) * 1024 + h * 64;   // K rows stride 1024
  const u16* Vg = VT + ((size_t)bh * 64) * 2048;             // VT rows (d) stride 2048

  // QK A-frag row constants
  const int r0 = ((l16 >> 2) << 3) + (l16 & 3);
  const int xpar = (l16 >> 2) & 1;
  const int swv = (l16 & 7) << 4;

  // staging: 256 threads, 2 rounds each of K and V (16B per thread per round)
  const int srow = tid >> 3;                 // 0..31
  const int scol = (tid & 7) ^ (srow & 7);   // pre-swizzled source chunk

  auto stage = [&](int jt, int bb) {
#pragma unroll
    for (int i = 0; i < 2; ++i) {
      int row = srow + i * 32;
      __builtin_amdgcn_global_load_lds(
          (const __attribute__((address_space(1))) void*)(Kg + ((size_t)(jt * 64 + row)) * 1024 + scol * 8),
          (__attribute__((address_space(3))) void*)(sK[bb] + w * 512 + i * 2048), 16, 0, 0);
      __builtin_amdgcn_global_load_lds(
          (const __attribute__((address_space(1))) void*)(Vg + ((size_t)row) * 2048 + jt * 64 + scol * 8),
          (__attribute__((address_space(3))) void*)(sV[bb] + w * 512 + i * 2048), 16, 0, 0);
    }
  };

  stage(0, 0);
  __syncthreads();

  int cur = 0;
  for (int jt = 0; jt < LKV_ / 64; ++jt) {
    if (jt < LKV_ / 64 - 1) stage(jt + 1, cur ^ 1);
    const char* kb = (const char*)sK[cur];
    const char* vb = (const char*)sV[cur];

    // ---- S^T - m = K_perm . Q^T + (-m_run) ----
    f32x4 sacc[4];
    const float mneg = -m_run;
#pragma unroll
    for (int ct = 0; ct < 4; ++ct) sacc[ct] = (f32x4){mneg, mneg, mneg, mneg};

    __builtin_amdgcn_s_setprio(1);
#pragma unroll
    for (int ct = 0; ct < 4; ++ct) {
      const int R = r0 + (((ct & 1) ^ xpar) << 2) + ((ct >> 1) << 5);
      const char* rp = kb + R * 128;
      const int sw = (R & 7) << 4;
      s16x8 ka0 = *reinterpret_cast<const s16x8*>(rp + ((lk * 16) ^ sw));
      s16x8 ka1 = *reinterpret_cast<const s16x8*>(rp + ((64 + lk * 16) ^ sw));
      sacc[ct] = __builtin_amdgcn_mfma_f32_16x16x32_bf16(ka0, qf[0], sacc[ct], 0, 0, 0);
      sacc[ct] = __builtin_amdgcn_mfma_f32_16x16x32_bf16(ka1, qf[1], sacc[ct], 0, 0, 0);
    }
    __builtin_amdgcn_s_setprio(0);

    // ---- online softmax (exp2 domain, defer-max THR=8, m pre-subtracted) ----
    {
      float mx = fmaxf(fmaxf(fmaxf(sacc[0][0], sacc[0][1]), fmaxf(sacc[0][2], sacc[0][3])),
                       fmaxf(fmaxf(sacc[1][0], sacc[1][1]), fmaxf(sacc[1][2], sacc[1][3])));
      mx = fmaxf(mx, fmaxf(fmaxf(fmaxf(sacc[2][0], sacc[2][1]), fmaxf(sacc[2][2], sacc[2][3])),
                           fmaxf(fmaxf(sacc[3][0], sacc[3][1]), fmaxf(sacc[3][2], sacc[3][3]))));
      mx = fmaxf(mx, __shfl_xor(mx, 16, 64));
      mx = fmaxf(mx, __shfl_xor(mx, 32, 64));
      if (!__all(mx <= 8.0f)) {
        float d = fmaxf(mx, 0.f);
        m_run += d;
        float sc = exp2f(-d);
        d_run *= sc;
#pragma unroll
        for (int dt = 0; dt < 4; ++dt) Oacc[dt] *= sc;
#pragma unroll
        for (int ct = 0; ct < 4; ++ct)
#pragma unroll
          for (int j = 0; j < 4; ++j) sacc[ct][j] -= d;
      }
      float ps = 0.f;
#pragma unroll
      for (int ct = 0; ct < 4; ++ct)
#pragma unroll
        for (int j = 0; j < 4; ++j) {
          float e = exp2f(sacc[ct][j]);
          sacc[ct][j] = e;
          ps += e;
        }
      ps += __shfl_xor(ps, 16, 64);
      ps += __shfl_xor(ps, 32, 64);
      d_run += ps;
    }

    // ---- O^T += VT . P^T (P stays in registers) ----
    const bool sel = (lk & 1) != 0;
#pragma unroll
    for (int f = 0; f < 2; ++f) {
      f32x4 pA = sel ? sacc[2 * f + 1] : sacc[2 * f];
      f32x4 pB = sel ? sacc[2 * f] : sacc[2 * f + 1];
      union { unsigned u[4]; s16x8 v; } pk;
      pk.u[0] = cvtpk(pA[0], pA[1]);
      pk.u[1] = cvtpk(pA[2], pA[3]);
      pk.u[2] = cvtpk(pB[0], pB[1]);
      pk.u[3] = cvtpk(pB[2], pB[3]);
      s16x8 pf = pk.v;
      __builtin_amdgcn_s_setprio(1);
#pragma unroll
      for (int dt = 0; dt < 4; ++dt) {
        const char* vrp = vb + (dt * 16 + l16) * 128;
        s16x8 va = *reinterpret_cast<const s16x8*>(vrp + ((f * 64 + lk * 16) ^ swv));
        Oacc[dt] = __builtin_amdgcn_mfma_f32_16x16x32_bf16(va, pf, Oacc[dt], 0, 0, 0);
      }
      __builtin_amdgcn_s_setprio(0);
    }
    __syncthreads();
    cur ^= 1;
  }

  // ---- epilogue: O[q=l16][d=16dt+4lk+j] / d_run ----
  u16* op = Rb + ((size_t)(b * LQ_ + qrow0 + l16)) * 1024 + h * 64 + lk * 4;
  float inv = 1.f / d_run;
#pragma unroll
  for (int dt = 0; dt < 4; ++dt) {
    ushort4 o;
    o.x = f2b(Oacc[dt][0] * inv);
    o.y = f2b(Oacc[dt][1] * inv);
    o.z = f2b(Oacc[dt][2] * inv);
    o.w = f2b(Oacc[dt][3] * inv);
    *reinterpret_cast<ushort4*>(op + dt * 16) = o;
  }
}

// ---------------- launch ----------------
extern "C" void kernel_launch(void* const* d_in, const int* in_sizes, int n_in,
                              void* d_out, int out_size, void* d_ws, size_t ws_size,
                              hipStream_t stream) {
  const float* x   = (const float*)d_in[0];
  const float* y   = (const float*)d_in[1];
  const float* Wq  = (const float*)d_in[2];
  const float* Wkv = (const float*)d_in[3];
  const float* Wp  = (const float*)d_in[4];
  const float* bp  = (const float*)d_in[5];
  float* out = (float*)d_out;

  u16* p = (u16*)d_ws;
  u16* xb   = p; p += (size_t)4096 * 1024;
  u16* yb   = p; p += (size_t)4096 * 768;
  u16* WqT  = p; p += (size_t)1024 * 1024;
  u16* WkvT = p; p += (size_t)2048 * 768;
  u16* WpT  = p; p += (size_t)1024 * 1024;
  u16* Qb   = p; p += (size_t)4096 * 1024;
  u16* Kbf  = p; p += (size_t)4096 * 1024;   // K compact [b*2048+kv][h*64+d]
  u16* VTb  = p; p += (size_t)4096 * 1024;   // [32][64][2048] = 4M elems
  u16* Rb   = p; p += (size_t)4096 * 1024;

  cast_bf16<<<4096, 256, 0, stream>>>(x, xb, 4096 * 1024);
  cast_bf16<<<3072, 256, 0, stream>>>(y, yb, 4096 * 768);
  transpose_cast<<<dim3(16, 16), 256, 0, stream>>>(Wq, WqT, 1024, 1024);
  transpose_cast<<<dim3(32, 12), 256, 0, stream>>>(Wkv, WkvT, 768, 2048);
  transpose_cast<<<dim3(16, 16), 256, 0, stream>>>(Wp, WpT, 1024, 1024);

  // Q = (x @ Wq) * 0.125*log2e : bf16 [4096,1024]
  gemm_bt<3><<<dim3(32, 16), 256, 0, stream>>>(xb, WqT, Qb, nullptr, nullptr, nullptr, 4096, 1024, 1024);
  // KV = y @ Wkv : K -> Kbf [4096,1024], V -> VTb [32][64][2048] (transposed in epilogue)
  gemm_bt<2><<<dim3(32, 32), 256, 0, stream>>>(yb, WkvT, Kbf, nullptr, nullptr, VTb, 4096, 2048, 768);
  // attention -> Rb [4096,1024]
  flash_attn<<<1024, 256, 0, stream>>>(Kbf, Qb, VTb, Rb);
  // out = Rb @ Wproj + bias : fp32 [4096,1024]
  gemm_bt<1><<<dim3(32, 16), 256, 0, stream>>>(Rb, WpT, nullptr, out, bp, nullptr, 4096, 1024, 1024);
}